// Round 3
// baseline (323.053 us; speedup 1.0000x reference)
//
#include <hip/hip_runtime.h>
#include <stdint.h>

#define Bsz 16384
#define Hsz 256
#define K1 1024
#define N1 1536
#define K2 512
#define N2 512

typedef __bf16 bf16x8 __attribute__((ext_vector_type(8)));
typedef float f32x4 __attribute__((ext_vector_type(4)));

__device__ __forceinline__ unsigned short f2bf(float f) {
    union { float f; unsigned int u; } v; v.f = f;
    unsigned int u = v.u;
    unsigned int r = (u + 0x7fffu + ((u >> 16) & 1u)) >> 16;
    return (unsigned short)r;
}

__device__ __forceinline__ float sigm(float x) {
    return 1.0f / (1.0f + __expf(-x));
}

// ============ fused weight/bias prep ============
// W1 [1536][1024] bf16, INTERLEAVED cols: n = g*512 + j*2 + part
//   (g: 0=r,1=z,2=h1; j=complex output idx; part: 0=re-out,1=im-out)
//   k<512 multiplies [x_re|h_re]; k>=512 multiplies [x_im|h_im].
//   part0: {wre, -wim}; part1: {wim, wre}
// W2 [512][512] bf16, cols n2 = j*2+part; rows: k2<256 -> rh_re, else rh_im.
// bias1[1536] f32 in same interleaved order (part0: bre-bim, part1: bre+bim).
__global__ void build_weights(
    const float* __restrict__ wr_re, const float* __restrict__ wr_im,
    const float* __restrict__ wz_re, const float* __restrict__ wz_im,
    const float* __restrict__ wh_re, const float* __restrict__ wh_im,
    const float* __restrict__ ur_re, const float* __restrict__ ur_im,
    const float* __restrict__ uz_re, const float* __restrict__ uz_im,
    const float* __restrict__ uh_re, const float* __restrict__ uh_im,
    const float* __restrict__ br_re, const float* __restrict__ br_im,
    const float* __restrict__ bz_re, const float* __restrict__ bz_im,
    const float* __restrict__ bh_re, const float* __restrict__ bh_im,
    unsigned short* __restrict__ W1, unsigned short* __restrict__ W2,
    float* __restrict__ bias1) {
    int idx = blockIdx.x * blockDim.x + threadIdx.x;
    if (idx < N1 * K1) {
        int n = idx / K1, k = idx % K1;
        int g = n >> 9, q = n & 511, j = q >> 1, part = q & 1;
        bool second = (k >= 512);
        int kk = k & 511;
        const float *Wre, *Wim, *Ure, *Uim;
        if (g == 0)      { Wre = wr_re; Wim = wr_im; Ure = ur_re; Uim = ur_im; }
        else if (g == 1) { Wre = wz_re; Wim = wz_im; Ure = uz_re; Uim = uz_im; }
        else             { Wre = wh_re; Wim = wh_im; Ure = uh_re; Uim = uh_im; }
        float wre, wim;
        if (g < 2) {
            wre = Wre[j * 512 + kk];
            wim = Wim[j * 512 + kk];
            if (kk >= 256) { wre += Ure[j * 256 + kk - 256]; wim += Uim[j * 256 + kk - 256]; }
        } else {
            if (kk < 256) { wre = Wre[j * 512 + kk];       wim = Wim[j * 512 + kk]; }
            else          { wre = Ure[j * 256 + kk - 256]; wim = Uim[j * 256 + kk - 256]; }
        }
        float val = (part == 0) ? (second ? -wim : wre) : (second ? wre : wim);
        W1[idx] = f2bf(val);
        return;
    }
    int i2 = idx - N1 * K1;
    if (i2 < N2 * K2) {
        int n2 = i2 / K2, k2 = i2 % K2;
        int j = n2 >> 1, part = n2 & 1;
        bool second = (k2 >= 256);
        int kk = k2 & 255;
        float wre = wh_re[j * 512 + 256 + kk];
        float wim = wh_im[j * 512 + 256 + kk];
        float val = (part == 0) ? (second ? -wim : wre) : (second ? wre : wim);
        W2[i2] = f2bf(val);
        return;
    }
    int i3 = i2 - N2 * K2;
    if (i3 < N1) {
        int g = i3 >> 9, q = i3 & 511, j = q >> 1, part = q & 1;
        const float* re = (g == 0) ? br_re : ((g == 1) ? bz_re : bh_re);
        const float* im = (g == 0) ? br_im : ((g == 1) ? bz_im : bh_im);
        bias1[i3] = part ? (re[j] + im[j]) : (re[j] - im[j]);
    }
}

// ============ A builder: A = [x_re|h_re|x_im|h_im] bf16 [B, 1024] ============
__global__ void build_a(const float* __restrict__ xr, const float* __restrict__ hr,
                        const float* __restrict__ xi, const float* __restrict__ hi,
                        unsigned short* __restrict__ a) {
    int idx = blockIdx.x * blockDim.x + threadIdx.x;
    if (idx >= Bsz * K1 / 4) return;
    int t = idx * 4;
    int b = t >> 10;
    int k = t & 1023;
    const float* src;
    int off;
    if (k < 256)      { src = xr; off = b * 256 + k; }
    else if (k < 512) { src = hr; off = b * 256 + k - 256; }
    else if (k < 768) { src = xi; off = b * 256 + k - 512; }
    else              { src = hi; off = b * 256 + k - 768; }
    f32x4 v = *(const f32x4*)(src + off);
    ushort4 o;
    o.x = f2bf(v[0]); o.y = f2bf(v[1]); o.z = f2bf(v[2]); o.w = f2bf(v[3]);
    *(ushort4*)(a + t) = o;
}

// ============ GEMM core: C[M,N] = A[M,K] * Bm[N,K]^T, fused epilogues ============
// 128x128 tile, BK=64, 256 thr (4 waves 2x2), mfma_f32_16x16x32_bf16.
// LDS [128][64] bf16 with XOR chunk swizzle: slot = chunk ^ (row&7)
// (write side pre-swizzles the GLOBAL chunk; LDS dest stays linear — m104/m173).
// MODE 1: gemm1 epilogue (g==0: rh->A2 bf16; g==1: C1z; g==2: C1h)
// MODE 2: gemm2 epilogue (z/tanh/h_new -> out), qc interleaved j*2+part.
template<int K, int NBX, int MODE>
__global__ __launch_bounds__(256)
void gemm_fused(const unsigned short* __restrict__ A,
                const unsigned short* __restrict__ Bm,
                const float* __restrict__ bias,
                const float* __restrict__ hre_g,
                const float* __restrict__ him_g,
                float* __restrict__ c1z,
                float* __restrict__ c1h,
                unsigned short* __restrict__ A2,
                float* __restrict__ outp) {
    __shared__ __align__(16) unsigned short sA[128 * 64];
    __shared__ __align__(16) unsigned short sB[128 * 64];
    const int tid  = threadIdx.x;
    const int lane = tid & 63;
    const int wid  = tid >> 6;

    // XCD-aware bijective swizzle (gridDim.x % 8 == 0 for all launches)
    const int nwg = gridDim.x;
    const int cpx = nwg >> 3;
    const int wgid = (blockIdx.x & 7) * cpx + (blockIdx.x >> 3);
    const int bx = wgid % NBX;
    const int by = wgid / NBX;
    const int rowA0 = by * 128;
    const int col0  = bx * 128;
    const int wm = (wid >> 1) * 64;
    const int wn = (wid & 1) * 64;

    f32x4 acc[4][4];
#pragma unroll
    for (int i = 0; i < 4; i++)
#pragma unroll
        for (int j = 0; j < 4; j++) acc[i][j] = {0.f, 0.f, 0.f, 0.f};

    // staging: wave wid owns rows [wid*32, wid*32+32); 8 rows per issue
    const int srow  = lane >> 3;                 // 0..7 within issue
    const int sgoff = ((lane & 7) ^ srow) * 8;   // pre-swizzled global chunk (shorts)
    // fragment indices
    const int fr = lane & 15;
    const int fc = lane >> 4;                    // 0..3

    for (int k0 = 0; k0 < K; k0 += 64) {
        __syncthreads();
#pragma unroll
        for (int i = 0; i < 4; i++) {
            int rl = wid * 32 + i * 8;
            const unsigned short* gp = A + (size_t)(rowA0 + rl + srow) * K + k0 + sgoff;
            unsigned short* lp = sA + rl * 64 + lane * 8;
            __builtin_amdgcn_global_load_lds((const __attribute__((address_space(1))) void*)gp,
                                             (__attribute__((address_space(3))) void*)lp,
                                             16, 0, 0);
        }
#pragma unroll
        for (int i = 0; i < 4; i++) {
            int rl = wid * 32 + i * 8;
            const unsigned short* gp = Bm + (size_t)(col0 + rl + srow) * K + k0 + sgoff;
            unsigned short* lp = sB + rl * 64 + lane * 8;
            __builtin_amdgcn_global_load_lds((const __attribute__((address_space(1))) void*)gp,
                                             (__attribute__((address_space(3))) void*)lp,
                                             16, 0, 0);
        }
        __syncthreads();

#pragma unroll
        for (int kk = 0; kk < 2; kk++) {
            bf16x8 af[4], bfr[4];
#pragma unroll
            for (int m = 0; m < 4; m++) {
                int r = wm + m * 16 + fr;
                int slot = (kk * 4 + fc) ^ (r & 7);
                af[m] = *(const bf16x8*)(sA + r * 64 + slot * 8);
            }
#pragma unroll
            for (int n = 0; n < 4; n++) {
                int r = wn + n * 16 + fr;
                int slot = (kk * 4 + fc) ^ (r & 7);
                bfr[n] = *(const bf16x8*)(sB + r * 64 + slot * 8);
            }
#pragma unroll
            for (int m = 0; m < 4; m++)
#pragma unroll
                for (int n = 0; n < 4; n++)
                    acc[m][n] = __builtin_amdgcn_mfma_f32_16x16x32_bf16(af[m], bfr[n], acc[m][n], 0, 0, 0);
        }
    }

    // epilogue: C/D layout col=lane&15, row=(lane>>4)*4+reg  [m89/m91]
    const int crow = (lane >> 4) * 4;
    const int ccol = lane & 15;

    if constexpr (MODE == 1) {
        const int g = col0 >> 9;   // 0=r, 1=z, 2=h1 (uniform per block)
#pragma unroll
        for (int m = 0; m < 4; m++) {
#pragma unroll
            for (int n = 0; n < 4; n++) {
                int nc = col0 + wn + n * 16 + ccol;    // global col
                int qc = nc & 511;                      // within-gate col
                int jj = qc >> 1;
                int part = qc & 1;
                float bv = bias[nc];
#pragma unroll
                for (int j = 0; j < 4; j++) {
                    int gr = rowA0 + wm + m * 16 + crow + j;
                    float v = acc[m][n][j] + bv;
                    if (g == 0) {
                        float s  = sigm(v);
                        float sp = __shfl_xor(s, 1);
                        float hr = hre_g[gr * 256 + jj];
                        float hi = him_g[gr * 256 + jj];
                        // even(part0): rr=s, ri=sp -> rh_re = s*hr - sp*hi
                        // odd (part1): ri=s, rr=sp -> rh_im = sp*hi + s*hr
                        float val = part ? (s * hr + sp * hi) : (s * hr - sp * hi);
                        A2[(size_t)gr * 512 + part * 256 + jj] = f2bf(val);
                    } else if (g == 1) {
                        c1z[(size_t)gr * 512 + qc] = v;
                    } else {
                        c1h[(size_t)gr * 512 + qc] = v;
                    }
                }
            }
        }
    } else {
#pragma unroll
        for (int m = 0; m < 4; m++) {
#pragma unroll
            for (int n = 0; n < 4; n++) {
                int qc = col0 + wn + n * 16 + ccol;     // 0..511 interleaved
                int jj = qc >> 1;
                int part = qc & 1;
#pragma unroll
                for (int j = 0; j < 4; j++) {
                    int gr = rowA0 + wm + m * 16 + crow + j;
                    float zpre = c1z[(size_t)gr * 512 + qc];
                    float hpre = c1h[(size_t)gr * 512 + qc] + acc[m][n][j];
                    float z  = sigm(zpre);
                    float hh = tanhf(hpre);
                    float zp  = __shfl_xor(z, 1);
                    float hhp = __shfl_xor(hh, 1);
                    float hr = hre_g[gr * 256 + jj];
                    float hi = him_g[gr * 256 + jj];
                    float res;
                    if (part == 0)
                        res = (1.f - z) * hr + zp * hi + z * hh - zp * hhp;
                    else
                        res = (1.f - zp) * hi - z * hr + zp * hh + z * hhp;
                    outp[(size_t)part * (Bsz * 256) + (size_t)gr * 256 + jj] = res;
                }
            }
        }
    }
}

extern "C" void kernel_launch(void* const* d_in, const int* in_sizes, int n_in,
                              void* d_out, int out_size, void* d_ws, size_t ws_size,
                              hipStream_t stream) {
    const float* x_re = (const float*)d_in[0];
    const float* x_im = (const float*)d_in[1];
    const float* h_re = (const float*)d_in[2];
    const float* h_im = (const float*)d_in[3];
    const float* wr_w_re = (const float*)d_in[4];
    const float* wr_w_im = (const float*)d_in[5];
    const float* wr_b_re = (const float*)d_in[6];
    const float* wr_b_im = (const float*)d_in[7];
    const float* wz_w_re = (const float*)d_in[8];
    const float* wz_w_im = (const float*)d_in[9];
    const float* wz_b_re = (const float*)d_in[10];
    const float* wz_b_im = (const float*)d_in[11];
    const float* wh_w_re = (const float*)d_in[12];
    const float* wh_w_im = (const float*)d_in[13];
    const float* wh_b_re = (const float*)d_in[14];
    const float* wh_b_im = (const float*)d_in[15];
    const float* ur_w_re = (const float*)d_in[16];
    const float* ur_w_im = (const float*)d_in[17];
    const float* uz_w_re = (const float*)d_in[18];
    const float* uz_w_im = (const float*)d_in[19];
    const float* uh_w_re = (const float*)d_in[20];
    const float* uh_w_im = (const float*)d_in[21];

    // ws layout (no aliasing: GEMM1 reads A while writing A2). Total 121,116,672 B.
    char* ws = (char*)d_ws;
    unsigned short* W1    = (unsigned short*)(ws);               //  3,145,728 B
    unsigned short* W2    = (unsigned short*)(ws + 3145728);     //    524,288 B
    float*          bias1 = (float*)         (ws + 3670016);     //      6,144 B
    unsigned short* A_bf  = (unsigned short*)(ws + 3676160);     // 33,554,432 B
    unsigned short* A2    = (unsigned short*)(ws + 37230592);    // 16,777,216 B
    float*          C1z   = (float*)         (ws + 54007808);    // 33,554,432 B
    float*          C1h   = (float*)         (ws + 87562240);    // 33,554,432 B

    const int prep_elems = N1 * K1 + N2 * K2 + N1;
    build_weights<<<(prep_elems + 255) / 256, 256, 0, stream>>>(
        wr_w_re, wr_w_im, wz_w_re, wz_w_im, wh_w_re, wh_w_im,
        ur_w_re, ur_w_im, uz_w_re, uz_w_im, uh_w_re, uh_w_im,
        wr_b_re, wr_b_im, wz_b_re, wz_b_im, wh_b_re, wh_b_im,
        W1, W2, bias1);

    build_a<<<(Bsz * K1 / 4 + 255) / 256, 256, 0, stream>>>(x_re, h_re, x_im, h_im, A_bf);

    gemm_fused<K1, N1 / 128, 1><<<(N1 / 128) * (Bsz / 128), 256, 0, stream>>>(
        A_bf, W1, bias1, h_re, h_im, C1z, C1h, A2, nullptr);

    gemm_fused<K2, N2 / 128, 2><<<(N2 / 128) * (Bsz / 128), 256, 0, stream>>>(
        A2, W2, nullptr, h_re, h_im, C1z, C1h, nullptr, (float*)d_out);
}